// Round 6
// baseline (310.894 us; speedup 1.0000x reference)
//
#include <hip/hip_runtime.h>
#include <hip/hip_bf16.h>

#define NB 4
#define PSEQ 4096
#define DK 64
#define DV 256

typedef __attribute__((ext_vector_type(8))) short short8;
typedef __attribute__((ext_vector_type(4))) float f32x4;

__device__ __forceinline__ float bf2f(unsigned short u) {
    union { unsigned int i; float f; } v; v.i = ((unsigned int)u) << 16; return v.f;
}
__device__ __forceinline__ unsigned short f2bf(float f) {
    union { float f; unsigned int i; } v; v.f = f;
    return (unsigned short)((v.i + 0x7fffu + ((v.i >> 16) & 1u)) >> 16);
}

// ---- fused prep (r4 version, verbatim): Q hi/lo, K->bf16, W->bf16, V^T ----
__global__ __launch_bounds__(256) void prep_all(
    const float* __restrict__ q, const float* __restrict__ k,
    const float* __restrict__ wfc, const float* __restrict__ v,
    unsigned short* __restrict__ Qh, unsigned short* __restrict__ Ql,
    unsigned short* __restrict__ Kh,
    unsigned short* __restrict__ Wb, unsigned short* __restrict__ Vt) {
    __shared__ float tile[64][65];
    const int b = blockIdx.x, tid = threadIdx.x;
    if (b < 1024) {                       // Q hi/lo split
        const int i = (b * 256 + tid) * 4;
        float4 x = *reinterpret_cast<const float4*>(q + i);
        ushort4 h, l;
        h.x = f2bf(x.x); l.x = f2bf(x.x - bf2f(h.x));
        h.y = f2bf(x.y); l.y = f2bf(x.y - bf2f(h.y));
        h.z = f2bf(x.z); l.z = f2bf(x.z - bf2f(h.z));
        h.w = f2bf(x.w); l.w = f2bf(x.w - bf2f(h.w));
        *reinterpret_cast<ushort4*>(Qh + i) = h;
        *reinterpret_cast<ushort4*>(Ql + i) = l;
    } else if (b < 2048) {                // K -> bf16
        const int i = ((b - 1024) * 256 + tid) * 4;
        float4 x = *reinterpret_cast<const float4*>(k + i);
        ushort4 h;
        h.x = f2bf(x.x); h.y = f2bf(x.y); h.z = f2bf(x.z); h.w = f2bf(x.w);
        *reinterpret_cast<ushort4*>(Kh + i) = h;
    } else if (b < 2112) {                // W -> bf16
        const int i = ((b - 2048) * 256 + tid) * 4;
        float4 x = *reinterpret_cast<const float4*>(wfc + i);
        ushort4 h;
        h.x = f2bf(x.x); h.y = f2bf(x.y); h.z = f2bf(x.z); h.w = f2bf(x.w);
        *reinterpret_cast<ushort4*>(Wb + i) = h;
    } else {                              // V transpose + cvt
        const int vtid = b - 2112;
        const int k0 = (vtid & 63) * 64, c0 = ((vtid >> 6) & 3) * 64, n = vtid >> 8;
        const float* vn = v + (size_t)n * PSEQ * DV;
        unsigned short* vtn = Vt + (size_t)n * DV * PSEQ;
        const int tx = tid & 15, ty = tid >> 4;
#pragma unroll
        for (int rep = 0; rep < 4; ++rep) {
            int r = ty + rep * 16;
            float4 d = *reinterpret_cast<const float4*>(vn + (size_t)(k0 + r) * DV + c0 + tx * 4);
            tile[r][tx * 4 + 0] = d.x; tile[r][tx * 4 + 1] = d.y;
            tile[r][tx * 4 + 2] = d.z; tile[r][tx * 4 + 3] = d.w;
        }
        __syncthreads();
#pragma unroll
        for (int rep = 0; rep < 4; ++rep) {
            int r2 = ty + rep * 16;
            ushort4 d;
            d.x = f2bf(tile[tx * 4 + 0][r2]); d.y = f2bf(tile[tx * 4 + 1][r2]);
            d.z = f2bf(tile[tx * 4 + 2][r2]); d.w = f2bf(tile[tx * 4 + 3][r2]);
            *reinterpret_cast<ushort4*>(vtn + (size_t)(c0 + r2) * PSEQ + k0 + tx * 4) = d;
        }
    }
}

// ---- attn partial: fat 32-row blocks, key-range halved, no DMA machinery ----
// 1024 blocks x 512 thr; block (h,n,qi) processes keys [h*2048, +2048) for
// q-rows [qi*32, +32). K/V/P all via plain loads (K,V are L2-resident; the
// global_load_lds path + vmcnt drains bought nothing -- r4 probes all null).
// LDS = P-exchange only (17KB) -> co-residency no longer LDS-capped; grid
// 1024 > 2/CU for the first time unconfounded (fat blocks keep V traffic
// identical to r4). One __syncthreads per body: write P(cc) -> sync ->
// same-body PV(cc). Double-buffered Pb makes the single barrier safe:
// wave X's write of Pb[b]@cc+2 is ordered after barrier@cc+1, which is after
// every wave's (lgkm-drained) reads of Pb[b]@cc.
// Partial O accumulated into d_out via f32 atomicAdd (out pre-zeroed);
// per-(h,ks4) row sums written non-atomically to Lp.
__global__ __launch_bounds__(512, 6) void attn_part(
    const unsigned short* __restrict__ Kh,
    const unsigned short* __restrict__ Qh,
    const unsigned short* __restrict__ Ql,
    const unsigned short* __restrict__ Vt,
    float* __restrict__ Lp,
    float* __restrict__ Og)
{
    __shared__ __align__(16) unsigned short Pb[2][32][132];   // 16896 B

    const int tid = threadIdx.x;
    const int w = tid >> 6;
    const int lane = tid & 63;
    const int ln = lane & 15;
    const int quad = lane >> 4;
    const int qs = w >> 2;        // q-subtile (0/1)
    const int ks4 = w & 3;        // key-subtile within chunk
    const int c0 = w * 32;        // PV channel stripe

    const int id = blockIdx.x;
    const int h  = id & 1;                // key half
    const int n  = (id >> 1) & 3;         // batch (XCD-pair locality for K/V)
    const int qi = id >> 3;               // 0..127
    const int q0 = qi * 32;

    const unsigned short* Khn = Kh + (size_t)n * PSEQ * DK;
    const unsigned short* Vn  = Vt + (size_t)n * DV * PSEQ;

    // persistent Q fragments, row q0+qs*16+ln
    short8 qhf[2], qlf[2];
#pragma unroll
    for (int ks = 0; ks < 2; ++ks) {
        const size_t a = (size_t)n * PSEQ * DK +
                         (size_t)(q0 + qs * 16 + ln) * DK + ks * 32 + quad * 8;
        qhf[ks] = *reinterpret_cast<const short8*>(Qh + a);
        qlf[ks] = *reinterpret_cast<const short8*>(Ql + a);
    }

    f32x4 oacc[2][2];
#pragma unroll
    for (int rb = 0; rb < 2; ++rb)
#pragma unroll
        for (int cb = 0; cb < 2; ++cb) oacc[rb][cb] = (f32x4){0.f, 0.f, 0.f, 0.f};
    float lsum = 0.f;
    const float SC = 0.125f * 1.44269504088896340736f;

#pragma unroll 1
    for (int cc = h * 16; cc < h * 16 + 16; ++cc) {
        const int b = cc & 1;
        const int kb = cc * 128;

        // K fragments direct from L2 (keys ks4*32+kt*16+ln of this chunk)
        short8 khf[2][2];
#pragma unroll
        for (int kt = 0; kt < 2; ++kt)
#pragma unroll
            for (int ks = 0; ks < 2; ++ks) {
                const int key = kb + ks4 * 32 + kt * 16 + ln;
                khf[kt][ks] = *reinterpret_cast<const short8*>(
                    Khn + (size_t)key * DK + ks * 32 + quad * 8);
            }

        f32x4 sac[2];
        __builtin_amdgcn_s_setprio(1);
#pragma unroll
        for (int kt = 0; kt < 2; ++kt) {
            f32x4 s = {0.f, 0.f, 0.f, 0.f};
#pragma unroll
            for (int ks = 0; ks < 2; ++ks) {
                s = __builtin_amdgcn_mfma_f32_16x16x32_bf16(khf[kt][ks], qhf[ks], s, 0, 0, 0);
                s = __builtin_amdgcn_mfma_f32_16x16x32_bf16(khf[kt][ks], qlf[ks], s, 0, 0, 0);
            }
            sac[kt] = s;
        }
        __builtin_amdgcn_s_setprio(0);

#pragma unroll
        for (int kt = 0; kt < 2; ++kt) {
            ushort4 pk;
            float p;
            p = exp2f(sac[kt][0] * SC); lsum += p; pk.x = f2bf(p);
            p = exp2f(sac[kt][1] * SC); lsum += p; pk.y = f2bf(p);
            p = exp2f(sac[kt][2] * SC); lsum += p; pk.z = f2bf(p);
            p = exp2f(sac[kt][3] * SC); lsum += p; pk.w = f2bf(p);
            *reinterpret_cast<ushort4*>(
                &Pb[b][qs * 16 + ln][ks4 * 32 + kt * 16 + quad * 4]) = pk;
        }

        __syncthreads();   // P(cc) visible

        // PV(cc): channels c0..c0+32, V direct from L2
        __builtin_amdgcn_s_setprio(1);
#pragma unroll
        for (int ks = 0; ks < 4; ++ks) {
            short8 v0 = *reinterpret_cast<const short8*>(
                Vn + (size_t)(c0 + ln) * PSEQ + kb + ks * 32 + quad * 8);
            short8 v1 = *reinterpret_cast<const short8*>(
                Vn + (size_t)(c0 + 16 + ln) * PSEQ + kb + ks * 32 + quad * 8);
            short8 pa[2];
#pragma unroll
            for (int rb = 0; rb < 2; ++rb)
                pa[rb] = *reinterpret_cast<const short8*>(&Pb[b][rb * 16 + ln][ks * 32 + quad * 8]);
#pragma unroll
            for (int rb = 0; rb < 2; ++rb) {
                oacc[rb][0] = __builtin_amdgcn_mfma_f32_16x16x32_bf16(pa[rb], v0, oacc[rb][0], 0, 0, 0);
                oacc[rb][1] = __builtin_amdgcn_mfma_f32_16x16x32_bf16(pa[rb], v1, oacc[rb][1], 0, 0, 0);
            }
        }
        __builtin_amdgcn_s_setprio(0);
    }

    // row-sum partial for this (h, ks4) stripe: reduce over quads, no atomic
    {
        float v = lsum;
        v += __shfl_xor(v, 16, 64);
        v += __shfl_xor(v, 32, 64);
        if (quad == 0)
            Lp[((((size_t)n * 128 + qi) * 2 + h) * 4 + ks4) * 32 + qs * 16 + ln] = v;
    }

    // accumulate O partial into pre-zeroed out buffer
#pragma unroll
    for (int rb = 0; rb < 2; ++rb)
#pragma unroll
        for (int i = 0; i < 4; ++i) {
            const size_t row = (size_t)n * PSEQ + q0 + rb * 16 + quad * 4 + i;
#pragma unroll
            for (int cb = 0; cb < 2; ++cb)
                atomicAdd(&Og[row * DV + c0 + cb * 16 + ln], oacc[rb][cb][i]);
        }
}

// ---- finish: normalize (sum of 8 Lp partials) + fc, overwrite out ----
__global__ __launch_bounds__(512) void finish_fc(
    const float* __restrict__ Lp,
    const unsigned short* __restrict__ Wg,
    const float* __restrict__ Bg,
    float* __restrict__ Og)
{
    __shared__ __align__(16) unsigned short Omrg[32][264];
    __shared__ float Lsh[32];

    const int tid = threadIdx.x;
    const int w = tid >> 6;
    const int lane = tid & 63;
    const int ln = lane & 15;
    const int quad = lane >> 4;
    const int c0 = w * 32;

    const int id = blockIdx.x;
    const int n = id & 3;
    const int qi = id >> 2;
    const int q0 = qi * 32;

    // read this block's 32x256 f32 partial O (before any write to out)
    const int r = tid >> 4;              // 0..31
    const int cb0 = (tid & 15) * 16;     // 16 floats per thread
    float x[16];
    {
        const float* orow = Og + ((size_t)n * PSEQ + q0 + r) * DV + cb0;
#pragma unroll
        for (int j = 0; j < 4; ++j)
            *reinterpret_cast<float4*>(&x[j * 4]) =
                *reinterpret_cast<const float4*>(orow + j * 4);
    }

    if (tid < 32) {
        float s = 0.f;
#pragma unroll
        for (int hh = 0; hh < 2; ++hh)
#pragma unroll
            for (int k4 = 0; k4 < 4; ++k4)
                s += Lp[((((size_t)n * 128 + qi) * 2 + hh) * 4 + k4) * 32 + tid];
        Lsh[tid] = s;
    }
    __syncthreads();

    const float il = 1.0f / Lsh[r];
#pragma unroll
    for (int j = 0; j < 16; ++j) Omrg[r][cb0 + j] = f2bf(x[j] * il);
    __syncthreads();

    // fc: out = O_norm @ W^T + b (same tile pattern as the r4 tail)
    short8 wf[2][8];
    float bb[2];
#pragma unroll
    for (int cb = 0; cb < 2; ++cb) {
        const int oc = c0 + cb * 16 + ln;
        bb[cb] = Bg[oc];
#pragma unroll
        for (int ks = 0; ks < 8; ++ks)
            wf[cb][ks] = *reinterpret_cast<const short8*>(Wg + (size_t)oc * DV + ks * 32 + quad * 8);
    }
#pragma unroll
    for (int rb = 0; rb < 2; ++rb) {
        short8 af[8];
#pragma unroll
        for (int ks = 0; ks < 8; ++ks)
            af[ks] = *reinterpret_cast<const short8*>(&Omrg[rb * 16 + ln][ks * 32 + quad * 8]);
        f32x4 fa0 = {0.f, 0.f, 0.f, 0.f}, fa1 = {0.f, 0.f, 0.f, 0.f};
#pragma unroll
        for (int ks = 0; ks < 8; ++ks) {
            fa0 = __builtin_amdgcn_mfma_f32_16x16x32_bf16(af[ks], wf[0][ks], fa0, 0, 0, 0);
            fa1 = __builtin_amdgcn_mfma_f32_16x16x32_bf16(af[ks], wf[1][ks], fa1, 0, 0, 0);
        }
#pragma unroll
        for (int i = 0; i < 4; ++i) {
            const size_t row = (size_t)n * PSEQ + q0 + rb * 16 + quad * 4 + i;
            Og[row * DV + c0 + ln]      = fa0[i] + bb[0];
            Og[row * DV + c0 + 16 + ln] = fa1[i] + bb[1];
        }
    }
}

extern "C" void kernel_launch(void* const* d_in, const int* in_sizes, int n_in,
                              void* d_out, int out_size, void* d_ws, size_t ws_size,
                              hipStream_t stream) {
    const float* k_src = (const float*)d_in[0];
    const float* v_src = (const float*)d_in[1];
    const float* q_tgr = (const float*)d_in[2];
    const float* W_fc  = (const float*)d_in[3];
    const float* b_fc  = (const float*)d_in[4];
    float* out = (float*)d_out;

    char* wsb = (char*)d_ws;
    unsigned short* Vt = (unsigned short*)(wsb);              //  8 MB: [n][c][k] bf16
    unsigned short* Qh = (unsigned short*)(wsb + 8388608);    //  2 MB
    unsigned short* Ql = (unsigned short*)(wsb + 10485760);   //  2 MB
    unsigned short* Kh = (unsigned short*)(wsb + 12582912);   //  2 MB
    unsigned short* Wb = (unsigned short*)(wsb + 14680064);   //  128 KB
    float*          Lp = (float*)(wsb + 14811136);            //  512 KB row-sum partials

    prep_all<<<3136, 256, 0, stream>>>(q_tgr, k_src, W_fc, v_src,
                                       Qh, Ql, Kh, Wb, Vt);
    hipMemsetAsync(d_out, 0, (size_t)out_size, stream);
    attn_part<<<1024, 512, 0, stream>>>(Kh, Qh, Ql, Vt, Lp, out);
    finish_fc<<<512, 512, 0, stream>>>(Lp, Wb, b_fc, out);
}